// Round 2
// baseline (196.613 us; speedup 1.0000x reference)
//
#include <hip/hip_runtime.h>
#include <hip/hip_bf16.h>

// B=8, Lq=2048, Lk=2048, D=256. out = softmax(mask? sq_i+sk_j : -1e9) @ V.
// sq cancels in softmax => out[i] = (mask[i]·(e*V)) / (mask[i]·e), e=exp(K·w).
// Stage 1: e_bf16 + evT (bf16, transposed K-major). Stage 2: LDS-free MFMA GEMM:
// both operands loaded straight into fragment layout from global (mask via
// int->bf16 cndmask, evT already k-contiguous), denominator folded into an
// extra MFMA accumulator whose B-frag is e in column 0. No barriers at all.
// Workspace: evT 8*256*2048*2 = 8 MB, e_bf16 8*2048*2 = 32 KB.

#define NB 8
#define LQ 2048
#define LK 2048
#define DD 256

typedef __attribute__((ext_vector_type(8))) short short8v;
typedef __attribute__((ext_vector_type(8))) unsigned short ushort8v;
typedef __attribute__((ext_vector_type(4))) float f32x4;

__device__ inline unsigned short f2bf(float x) {
  union { __hip_bfloat16 h; unsigned short u; } cv;
  cv.h = __float2bfloat16(x);
  return cv.u;
}

// ---------------- Stage 1: e = exp(K·w) (bf16); evT[b][d][j] = bf16(e_j*V[j][d]) --
__global__ __launch_bounds__(256) void bah_precompute(
    const float* __restrict__ key, const float* __restrict__ value,
    const float* __restrict__ w, unsigned short* __restrict__ evT,
    unsigned short* __restrict__ eb)
{
  __shared__ float w_s[DD];
  __shared__ unsigned short t_s[64][DD];   // [j_local][d] transpose buffer

  const int t = threadIdx.x;
  const int lane = t & 63;
  const int wid = t >> 6;
  const int blk = blockIdx.x;
  const int b = blk & 7;                   // batch -> XCD locality
  const int j0 = (blk >> 3) * 64;

  w_s[t] = w[t];
  __syncthreads();
  const float4 wv4 = reinterpret_cast<const float4*>(w_s)[lane];

  for (int it = 0; it < 16; ++it) {
    const int r = it * 4 + wid;
    const size_t row = (size_t)b * LK + (j0 + r);
    const float4 kv = reinterpret_cast<const float4*>(key + row * DD)[lane];
    float s = kv.x * wv4.x + kv.y * wv4.y + kv.z * wv4.z + kv.w * wv4.w;
#pragma unroll
    for (int off = 32; off; off >>= 1) s += __shfl_xor(s, off);
    const float e = __expf(s);             // |K·w| small: no max-shift needed
    if (lane == 0) eb[row] = f2bf(e);
    const float4 vv = reinterpret_cast<const float4*>(value + row * DD)[lane];
    ushort4 u;
    u.x = f2bf(e * vv.x);
    u.y = f2bf(e * vv.y);
    u.z = f2bf(e * vv.z);
    u.w = f2bf(e * vv.w);
    *reinterpret_cast<ushort4*>(&t_s[r][lane * 4]) = u;
  }
  __syncthreads();

  const int d = t;
  unsigned short* dst = evT + ((size_t)b * DD + d) * LK + j0;
#pragma unroll
  for (int s8 = 0; s8 < 8; ++s8) {
    ushort8v val;
#pragma unroll
    for (int c = 0; c < 8; ++c) val[c] = t_s[s8 * 8 + c][d];
    *reinterpret_cast<ushort8v*>(dst + s8 * 8) = val;
  }
}

// ---------------- Stage 2: LDS-free masked GEMM --------------------------------
// 1024 blocks x 256 thr (4 waves). Wave tile: 16 rows x 64 d. 4 blocks/CU.
// A-frag (16x16x32): lane holds mask[i0 + (lane&15)][k + (lane>>4)*8 .. +7].
// B-frag: lane holds evT[b][d=wn*64+n*16+(lane&15)][k + (lane>>4)*8 .. +7].
// Denominator: extra accumulator with B-frag = e_bf16 in col 0, zeros elsewhere.
__global__ __launch_bounds__(256, 4) void bah_gemm(
    const int* __restrict__ mask, const unsigned short* __restrict__ evT,
    const unsigned short* __restrict__ eb, float* __restrict__ out)
{
  const int t = threadIdx.x;
  const int lane = t & 63;
  const int wn = t >> 6;                  // 0..3: d quarter
  const int blk = blockIdx.x;
  const int b = blk & 7;                  // batch -> XCD locality (evT L2-resident)
  const int i0 = (blk >> 3) * 16;

  const int lr = lane & 15;
  const int lk = (lane >> 4) * 8;

  const int* aptr = mask + ((size_t)b * LQ + i0 + lr) * LK + lk;
  const unsigned short* bptr0 = evT + ((size_t)b * DD + wn * 64 + lr) * LK + lk;
  const unsigned short* bptr1 = bptr0 + 16 * LK;
  const unsigned short* bptr2 = bptr0 + 32 * LK;
  const unsigned short* bptr3 = bptr0 + 48 * LK;
  const unsigned short* eptr = eb + (size_t)b * LK + lk;
  const bool elane = (lr == 0);

  f32x4 acc0 = {}, acc1 = {}, acc2 = {}, acc3 = {}, accd = {};
  const short8v zero8 = {};

  for (int k = 0; k < LK; k += 64) {
#pragma unroll
    for (int h = 0; h < 2; ++h) {
      const int off = h * 32;
      // ---- issue all loads first ----
      const int4 a0 = *reinterpret_cast<const int4*>(aptr + off);
      const int4 a1 = *reinterpret_cast<const int4*>(aptr + off + 4);
      const short8v bf0 = *reinterpret_cast<const short8v*>(bptr0 + off);
      const short8v bf1 = *reinterpret_cast<const short8v*>(bptr1 + off);
      const short8v bf2 = *reinterpret_cast<const short8v*>(bptr2 + off);
      const short8v bf3 = *reinterpret_cast<const short8v*>(bptr3 + off);
      short8v ef = *reinterpret_cast<const short8v*>(eptr + off);
      ef = elane ? ef : zero8;            // e only in output col 0
      // ---- mask -> bf16 {0,1} fragment ----
      short8v af;
      af[0] = a0.x ? (short)0x3F80 : (short)0;
      af[1] = a0.y ? (short)0x3F80 : (short)0;
      af[2] = a0.z ? (short)0x3F80 : (short)0;
      af[3] = a0.w ? (short)0x3F80 : (short)0;
      af[4] = a1.x ? (short)0x3F80 : (short)0;
      af[5] = a1.y ? (short)0x3F80 : (short)0;
      af[6] = a1.z ? (short)0x3F80 : (short)0;
      af[7] = a1.w ? (short)0x3F80 : (short)0;
      // ---- 5 independent accumulator chains ----
      acc0 = __builtin_amdgcn_mfma_f32_16x16x32_bf16(af, bf0, acc0, 0, 0, 0);
      acc1 = __builtin_amdgcn_mfma_f32_16x16x32_bf16(af, bf1, acc1, 0, 0, 0);
      acc2 = __builtin_amdgcn_mfma_f32_16x16x32_bf16(af, bf2, acc2, 0, 0, 0);
      acc3 = __builtin_amdgcn_mfma_f32_16x16x32_bf16(af, bf3, acc3, 0, 0, 0);
      accd = __builtin_amdgcn_mfma_f32_16x16x32_bf16(af, ef, accd, 0, 0, 0);
    }
    aptr += 64;
    bptr0 += 64; bptr1 += 64; bptr2 += 64; bptr3 += 64;
    eptr += 64;
  }

  // ---- epilogue: denom broadcast (col 0 lives in lane (lane>>4)*16) ----
  float inv[4];
#pragma unroll
  for (int r = 0; r < 4; ++r) {
    const float dn = __shfl(accd[r], lane & 48);
    inv[r] = (dn != 0.f) ? 1.f / dn : 0.f;   // all-masked row: avoid NaN
  }
  // C layout: col = lane&15, row = (lane>>4)*4 + r
  float* obase = out + ((size_t)b * LQ + i0 + (lane >> 4) * 4) * DD + wn * 64 + lr;
#pragma unroll
  for (int r = 0; r < 4; ++r) {
    obase[r * DD +  0] = acc0[r] * inv[r];
    obase[r * DD + 16] = acc1[r] * inv[r];
    obase[r * DD + 32] = acc2[r] * inv[r];
    obase[r * DD + 48] = acc3[r] * inv[r];
  }
}

extern "C" void kernel_launch(void* const* d_in, const int* in_sizes, int n_in,
                              void* d_out, int out_size, void* d_ws, size_t ws_size,
                              hipStream_t stream) {
  // inputs: 0=query (unused: softmax shift-invariance), 1=key, 2=value, 3=mask, 4=w_align
  const float* key   = (const float*)d_in[1];
  const float* value = (const float*)d_in[2];
  const int*   mask  = (const int*)d_in[3];
  const float* w     = (const float*)d_in[4];
  float* out = (float*)d_out;

  unsigned short* evT = (unsigned short*)d_ws;                              // 8 MB
  unsigned short* eb  = (unsigned short*)((char*)d_ws + (size_t)NB * DD * LK * 2);

  bah_precompute<<<NB * (LK / 64), 256, 0, stream>>>(key, value, w, evT, eb);
  bah_gemm<<<NB * (LQ / 16), 256, 0, stream>>>(mask, evT, eb, out);
}

// Round 3
// 62.410 us; speedup vs baseline: 3.1504x; 3.1504x over previous
//
#include <hip/hip_runtime.h>
#include <hip/hip_bf16.h>

// B=8, Lq=2048, Lk=2048, D=256. out = softmax(mask? sq_i+sk_j : -1e9) @ V.
// sq cancels in softmax => out[i] = (mask[i]·(e*V)) / (mask[i]·e), e=exp(K·w).
// Stage 1: e_bf16 + evT (bf16, transposed K-major). Stage 2: pipelined 2-phase
// MFMA GEMM: double-buffered LDS, stage(t+1) issued before compute(t), ONE
// barrier per K-step. B staged via global_load_lds (pre-swizzled source, linear
// dest); A (mask) reg-staged with late convert+ds_write. Denominator folded
// into MFMA (e-column B-frag) on wn==0 waves.
// Workspace: evT 8*256*2048*2 = 8 MB, e_bf16 8*2048*2 = 32 KB.

#define NB 8
#define LQ 2048
#define LK 2048
#define DD 256

typedef __attribute__((ext_vector_type(8))) short short8v;
typedef __attribute__((ext_vector_type(8))) unsigned short ushort8v;
typedef __attribute__((ext_vector_type(4))) float f32x4;

__device__ inline unsigned short f2bf(float x) {
  union { __hip_bfloat16 h; unsigned short u; } cv;
  cv.h = __float2bfloat16(x);
  return cv.u;
}

__device__ inline void gld_lds16(const unsigned short* g, unsigned short* l) {
  __builtin_amdgcn_global_load_lds(
      (const __attribute__((address_space(1))) void*)g,
      (__attribute__((address_space(3))) void*)l, 16, 0, 0);
}

// ---------------- Stage 1: e = exp(K·w) (bf16); evT[b][d][j] = bf16(e_j*V[j][d]) --
__global__ __launch_bounds__(256) void bah_precompute(
    const float* __restrict__ key, const float* __restrict__ value,
    const float* __restrict__ w, unsigned short* __restrict__ evT,
    unsigned short* __restrict__ eb)
{
  __shared__ float w_s[DD];
  __shared__ unsigned short t_s[64][DD];   // [j_local][d] transpose buffer

  const int t = threadIdx.x;
  const int lane = t & 63;
  const int wid = t >> 6;
  const int blk = blockIdx.x;
  const int b = blk & 7;                   // batch -> XCD locality
  const int j0 = (blk >> 3) * 64;

  w_s[t] = w[t];
  __syncthreads();
  const float4 wv4 = reinterpret_cast<const float4*>(w_s)[lane];

  for (int it = 0; it < 16; ++it) {
    const int r = it * 4 + wid;
    const size_t row = (size_t)b * LK + (j0 + r);
    const float4 kv = reinterpret_cast<const float4*>(key + row * DD)[lane];
    float s = kv.x * wv4.x + kv.y * wv4.y + kv.z * wv4.z + kv.w * wv4.w;
#pragma unroll
    for (int off = 32; off; off >>= 1) s += __shfl_xor(s, off);
    const float e = __expf(s);             // |K·w| small: no max-shift needed
    if (lane == 0) eb[row] = f2bf(e);
    const float4 vv = reinterpret_cast<const float4*>(value + row * DD)[lane];
    ushort4 u;
    u.x = f2bf(e * vv.x);
    u.y = f2bf(e * vv.y);
    u.z = f2bf(e * vv.z);
    u.w = f2bf(e * vv.w);
    *reinterpret_cast<ushort4*>(&t_s[r][lane * 4]) = u;
  }
  __syncthreads();

  const int d = t;
  unsigned short* dst = evT + ((size_t)b * DD + d) * LK + j0;
#pragma unroll
  for (int s8 = 0; s8 < 8; ++s8) {
    ushort8v val;
#pragma unroll
    for (int c = 0; c < 8; ++c) val[c] = t_s[s8 * 8 + c][d];
    *reinterpret_cast<ushort8v*>(dst + s8 * 8) = val;
  }
}

// ---------------- Stage 2: pipelined masked GEMM ------------------------------
// BM=64, BN=256, BK=64, 512 thr (8 waves, 2m x 4n), wave tile 32x64.
// grid = 8 batches x 32 i-blocks = 256 = 1 block/CU; blk&7 = batch = XCD.
__global__ __launch_bounds__(512, 2) void bah_gemm(
    const int* __restrict__ mask, const unsigned short* __restrict__ evT,
    const unsigned short* __restrict__ eb, float* __restrict__ out)
{
  __shared__ unsigned short A_s[2][64 * 64];    // mask tile bf16, swizzled (16 KB)
  __shared__ unsigned short B_s[2][DD * 64];    // evT tile, swizzled image (64 KB)
  __shared__ unsigned short e_s[LK];            // full e row (4 KB)
  __shared__ float denom_s[64];

  const int t = threadIdx.x;
  const int lane = t & 63;
  const int wid = t >> 6;
  const int wm = wid >> 2;                  // 0..1
  const int wn = wid & 3;                   // 0..3
  const int lr = lane & 15;
  const int lk = (lane >> 4) * 8;

  const int blk = blockIdx.x;
  const int b = blk & 7;                    // batch -> XCD (evT L2-resident)
  const int i0 = (blk >> 3) * 64;

  // A staging: thread -> row sr (8 thr/row), 8 ints at sc
  const int sr = t >> 3;
  const int sc = (t & 7) * 8;
  const int sslot = (((t & 7) ^ (sr & 7)) * 8);            // swizzled ushort slot
  const int* mrow = mask + ((size_t)b * LQ + (i0 + sr)) * LK;

  // B staging: wave stages d-rows [wid*32, wid*32+32), 4 gload_lds x (8 rows)
  const unsigned short* evTb = evT + (size_t)b * DD * LK;
  const int bswz = ((lane & 7) ^ (lane >> 3)) * 8;         // pre-swizzled src chunk
  const int brow0 = wid * 32;
  const int brl = lane >> 3;                               // row within 8-row group

  // e_s fill (once): 512 thr x 4 ushorts
  *reinterpret_cast<ushort4*>(&e_s[t * 4]) =
      *reinterpret_cast<const ushort4*>(eb + (size_t)b * LK + t * 4);

  // ---- prologue: stage tile 0 into buf 0 ----
  {
    const int4 a0 = *reinterpret_cast<const int4*>(mrow + sc);
    const int4 a1 = *reinterpret_cast<const int4*>(mrow + sc + 4);
#pragma unroll
    for (int s = 0; s < 4; ++s)
      gld_lds16(evTb + (size_t)(brow0 + s * 8 + brl) * LK + bswz,
                &B_s[0][(brow0 + s * 8) * 64]);
    ushort8v au;
    au[0] = a0.x ? 0x3F80 : 0;  au[1] = a0.y ? 0x3F80 : 0;
    au[2] = a0.z ? 0x3F80 : 0;  au[3] = a0.w ? 0x3F80 : 0;
    au[4] = a1.x ? 0x3F80 : 0;  au[5] = a1.y ? 0x3F80 : 0;
    au[6] = a1.z ? 0x3F80 : 0;  au[7] = a1.w ? 0x3F80 : 0;
    *reinterpret_cast<ushort8v*>(&A_s[0][sr * 64 + sslot]) = au;
  }
  __syncthreads();

  f32x4 acc[2][4] = {};
  f32x4 accd[2] = {};
  int buf = 0;

  for (int t32 = 0; t32 < 32; ++t32) {
    const int k0 = t32 * 64;
    const int kn = (t32 == 31) ? 0 : k0 + 64;   // last stage wraps (harmless)

    // ---- issue stage(t+1) loads FIRST: A to regs, B direct-to-LDS ----
    const int4 a0 = *reinterpret_cast<const int4*>(mrow + kn + sc);
    const int4 a1 = *reinterpret_cast<const int4*>(mrow + kn + sc + 4);
    unsigned short* Bd = &B_s[buf ^ 1][0];
#pragma unroll
    for (int s = 0; s < 4; ++s)
      gld_lds16(evTb + (size_t)(brow0 + s * 8 + brl) * LK + kn + bswz,
                Bd + (brow0 + s * 8) * 64);

    // ---- compute tile t from buf ----
    const unsigned short* As = &A_s[buf][0];
    const unsigned short* Bs = &B_s[buf][0];
#pragma unroll
    for (int kk = 0; kk < 64; kk += 32) {
      const int kr = kk + lk;
      short8v af[2], bfv[4];
#pragma unroll
      for (int m = 0; m < 2; ++m) {
        const int row = wm * 32 + m * 16 + lr;
        af[m] = *reinterpret_cast<const short8v*>(&As[row * 64 + (kr ^ ((row & 7) * 8))]);
      }
#pragma unroll
      for (int n = 0; n < 4; ++n) {
        const int d = wn * 64 + n * 16 + lr;
        bfv[n] = *reinterpret_cast<const short8v*>(&Bs[d * 64 + (kr ^ ((d & 7) * 8))]);
      }
      if (wn == 0) {                        // denominator: e-column B-frag
        const short8v z8 = {};
        short8v ev = *reinterpret_cast<const short8v*>(&e_s[k0 + kr]);
        ev = (lr == 0) ? ev : z8;
#pragma unroll
        for (int m = 0; m < 2; ++m)
          accd[m] = __builtin_amdgcn_mfma_f32_16x16x32_bf16(af[m], ev, accd[m], 0, 0, 0);
      }
#pragma unroll
      for (int m = 0; m < 2; ++m)
#pragma unroll
        for (int n = 0; n < 4; ++n)
          acc[m][n] = __builtin_amdgcn_mfma_f32_16x16x32_bf16(af[m], bfv[n], acc[m][n], 0, 0, 0);
    }

    // ---- finish stage(t+1): convert mask -> bf16, write to buf^1 ----
    ushort8v au;
    au[0] = a0.x ? 0x3F80 : 0;  au[1] = a0.y ? 0x3F80 : 0;
    au[2] = a0.z ? 0x3F80 : 0;  au[3] = a0.w ? 0x3F80 : 0;
    au[4] = a1.x ? 0x3F80 : 0;  au[5] = a1.y ? 0x3F80 : 0;
    au[6] = a1.z ? 0x3F80 : 0;  au[7] = a1.w ? 0x3F80 : 0;
    *reinterpret_cast<ushort8v*>(&A_s[buf ^ 1][sr * 64 + sslot]) = au;

    __syncthreads();   // drains vmcnt (gload_lds) + lgkm (ds_write): buf^1 ready
    buf ^= 1;
  }

  // ---- denominator broadcast ----
  if (wn == 0 && lr == 0) {
#pragma unroll
    for (int m = 0; m < 2; ++m)
#pragma unroll
      for (int r = 0; r < 4; ++r)
        denom_s[wm * 32 + m * 16 + (lane >> 4) * 4 + r] = accd[m][r];
  }
  __syncthreads();

  // ---- epilogue: divide and store (C layout: col=lane&15, row=(lane>>4)*4+r) --
#pragma unroll
  for (int m = 0; m < 2; ++m) {
    const int row0 = wm * 32 + m * 16 + ((lane >> 4) << 2);
    float inv[4];
#pragma unroll
    for (int r = 0; r < 4; ++r) {
      const float dn = denom_s[row0 + r];
      inv[r] = (dn != 0.f) ? 1.f / dn : 0.f;   // all-masked row: avoid NaN
    }
#pragma unroll
    for (int n = 0; n < 4; ++n) {
      const int col = wn * 64 + n * 16 + lr;
#pragma unroll
      for (int r = 0; r < 4; ++r)
        out[((size_t)b * LQ + (i0 + row0 + r)) * DD + col] = acc[m][n][r] * inv[r];
    }
  }
}

extern "C" void kernel_launch(void* const* d_in, const int* in_sizes, int n_in,
                              void* d_out, int out_size, void* d_ws, size_t ws_size,
                              hipStream_t stream) {
  // inputs: 0=query (unused: softmax shift-invariance), 1=key, 2=value, 3=mask, 4=w_align
  const float* key   = (const float*)d_in[1];
  const float* value = (const float*)d_in[2];
  const int*   mask  = (const int*)d_in[3];
  const float* w     = (const float*)d_in[4];
  float* out = (float*)d_out;

  unsigned short* evT = (unsigned short*)d_ws;                              // 8 MB
  unsigned short* eb  = (unsigned short*)((char*)d_ws + (size_t)NB * DD * LK * 2);

  bah_precompute<<<NB * (LK / 64), 256, 0, stream>>>(key, value, w, evT, eb);
  bah_gemm<<<NB * (LQ / 64), 512, 0, stream>>>(mask, evT, eb, out);
}